// Round 5
// baseline (185.732 us; speedup 1.0000x reference)
//
#include <hip/hip_runtime.h>
#include <stdint.h>

#define N_NODES 50000
#define N_EDGES 800000
#define CAP 80        // bucket capacity; deg ~ Poisson(16), P(deg>80) ~ 1e-25
#define ZROW N_NODES  // zero-row index used to pad gather loops (rows 50000..50047 zeroed)
#define NBIN 196      // coarse dst bins: bin = dst>>8; 196*256 = 50176 covers nodes+pads
#define NBLK_A 128    // histogram/scatter blocks
#define EPB 6250      // edges per block: 128*6250 = 800000
#define GEMM_BLOCKS 782   // 50048/64
// R5: device-scope atomic CSR build (52us, fabric-transaction-bound per R1/R4 probes)
// replaced by deterministic 3-phase binned build: LDS-histogram -> scan -> LDS-cursor
// scatter -> per-bin LDS-atomic CSR. Zero device-scope atomics.
// D_IN=128, H1=128, H2=64, C=2 — inputs fp32; intermediates bf16 (h1s UNscaled, h2s dinv-prescaled)

typedef __attribute__((ext_vector_type(8))) short short8;     // 8 bf16 (4 VGPRs)
typedef __attribute__((ext_vector_type(4))) float floatx4;    // MFMA acc

// ---------- bf16 helpers ----------
__device__ __forceinline__ float bflo(uint32_t u) { return __uint_as_float(u << 16); }
__device__ __forceinline__ float bfhi(uint32_t u) { return __uint_as_float(u & 0xffff0000u); }
__device__ __forceinline__ unsigned short f2b(float f) {
    uint32_t u = __float_as_uint(f);
    u += 0x7fffu + ((u >> 16) & 1u);   // RNE
    return (unsigned short)(u >> 16);
}

// ---------- 1. prep: blocks 0..127 bin-histogram (LDS atomics); 128..223 Wt transposes ----------
__global__ __launch_bounds__(256) void k_prep(const float* __restrict__ W1,
                                              const float* __restrict__ W2,
                                              unsigned short* __restrict__ Wt1,
                                              unsigned short* __restrict__ Wt2,
                                              const int* __restrict__ dst,
                                              int* __restrict__ mat) {
    __shared__ int h[NBIN];
    int t = threadIdx.x, blk = blockIdx.x;
    if (blk < NBLK_A) {
        if (t < NBIN) h[t] = 0;
        __syncthreads();
        int e0 = blk * EPB;
        for (int i = t; i < EPB; i += 256) atomicAdd(&h[dst[e0 + i] >> 8], 1);
        __syncthreads();
        if (t < NBIN) mat[blk * NBIN + t] = h[t];   // [blk][bin], coalesced
        return;
    }
    int gid = (blk - NBLK_A) * 256 + t;
    if (gid < 16384) {                     // Wt1[n][k] = bf16(W1[k][n])
        int k = gid >> 7, n = gid & 127;
        Wt1[n * 128 + k] = f2b(W1[gid]);
    } else if (gid < 24576) {              // Wt2[n][k] = bf16(W2[k][n])
        int j = gid - 16384;
        int k = j >> 6, n = j & 63;
        Wt2[n * 128 + k] = f2b(W2[j]);
    }
}

// ---------- 2. scan: mat[blk][bin] -> exclusive global bases; binStart[NBIN+1] ----------
__global__ __launch_bounds__(256) void k_scan(int* __restrict__ mat,
                                              int* __restrict__ binStart) {
    __shared__ int tot[256];
    int b = threadIdx.x;
    int base = 0;
    if (b < NBIN) {
        #pragma unroll 8
        for (int k = 0; k < NBLK_A; k++) {      // coalesced across threads at fixed k
            int v = mat[k * NBIN + b];
            mat[k * NBIN + b] = base;
            base += v;
        }
    }
    tot[b] = (b < NBIN) ? base : 0;
    __syncthreads();
    if (b == 0) {
        int r = 0;
        for (int i = 0; i < NBIN; i++) { int v = tot[i]; tot[i] = r; r += v; }
    }
    __syncthreads();
    if (b < NBIN) {
        int bb = tot[b];
        binStart[b] = bb;
        #pragma unroll 8
        for (int k = 0; k < NBLK_A; k++) mat[k * NBIN + b] += bb;
        if (b == NBIN - 1) binStart[NBIN] = bb + base;   // = N_EDGES
    }
}

// ---------- 3. binned scatter: LDS cursors, deterministic slots, no global atomics ----------
__global__ __launch_bounds__(256) void k_binscat(const int* __restrict__ src,
                                                 const int* __restrict__ dst,
                                                 const int* __restrict__ mat,
                                                 int2* __restrict__ binned) {
    __shared__ int cur[NBIN];
    int t = threadIdx.x, blk = blockIdx.x;
    if (t < NBIN) cur[t] = mat[blk * NBIN + t];
    __syncthreads();
    int e0 = blk * EPB;
    for (int i = t; i < EPB; i += 256) {
        int d = dst[e0 + i], s = src[e0 + i];
        int slot = atomicAdd(&cur[d >> 8], 1);   // LDS atomic
        binned[slot] = make_int2(s, d);
    }
}

// ---------- 4. FUSED: per-bin CSR build (blocks 0..195) || gemm1 (196..977) ----------
// CSR: bin b owns nodes [b*256, b*256+256); LDS cnt[256] ranks edges; csr rows are
// 320B line-aligned, disjoint per bin. counts written wholesale (pads = 0 free).
// gemm1: h1s[v] = bf16(x[v]) @ bf16(W1), UNSCALED; 64 rows/block; zeroes pad rows.
__global__ __launch_bounds__(256) void k_csr_gemm1(const int2* __restrict__ binned,
                                                   const int* __restrict__ binStart,
                                                   int* __restrict__ counts,
                                                   int* __restrict__ csr,
                                                   const float* __restrict__ x,
                                                   const unsigned short* __restrict__ Wt1,
                                                   unsigned short* __restrict__ h1s,
                                                   unsigned short* __restrict__ h2s) {
    __shared__ unsigned short At[64 * 136];   // 17.0 KB (pad 8 bf16)
    __shared__ unsigned short Bt[128 * 136];  // 34.0 KB
    __shared__ int cnt[256];
    int t = threadIdx.x;
    if (blockIdx.x < NBIN) {
        cnt[t] = 0;
        __syncthreads();
        int b = blockIdx.x;
        int st = binStart[b], en = binStart[b + 1];
        for (int i = st + t; i < en; i += 256) {
            int2 e = binned[i];
            int r = atomicAdd(&cnt[e.y & 255], 1);   // LDS atomic rank
            if (r < CAP) csr[e.y * CAP + r] = e.x;
        }
        __syncthreads();
        counts[b * 256 + t] = cnt[t];                // covers all 50176 incl. zero pads
        return;
    }
    // ---- gemm1 ----
    int row0 = (blockIdx.x - NBIN) * 64;
    for (int i = t; i < 2048; i += 256) {     // stage Bt (Wt1 [n][k] bf16)
        int n = i >> 4, kc = (i & 15) * 8;
        *(uint4*)&Bt[n * 136 + kc] = *(const uint4*)(Wt1 + n * 128 + kc);
    }
    for (int i = t; i < 1024; i += 256) {     // stage At: fp32 -> bf16
        int r = i >> 4, kc = (i & 15) * 8;
        int g = row0 + r; if (g >= N_NODES) g = N_NODES - 1;
        const float* p = x + g * 128 + kc;
        float4 a = *(const float4*)p, b = *(const float4*)(p + 4);
        uint4 o;
        o.x = (uint32_t)f2b(a.x) | ((uint32_t)f2b(a.y) << 16);
        o.y = (uint32_t)f2b(a.z) | ((uint32_t)f2b(a.w) << 16);
        o.z = (uint32_t)f2b(b.x) | ((uint32_t)f2b(b.y) << 16);
        o.w = (uint32_t)f2b(b.z) | ((uint32_t)f2b(b.w) << 16);
        *(uint4*)&At[r * 136 + kc] = o;
    }
    __syncthreads();
    int wv = t >> 6, lane = t & 63;
    int m = lane & 15, qd = lane >> 4;
    floatx4 acc[8];
    #pragma unroll
    for (int c = 0; c < 8; c++) acc[c] = (floatx4){0.f, 0.f, 0.f, 0.f};
    const unsigned short* ap = &At[(wv * 16 + m) * 136 + qd * 8];
    const unsigned short* bp = &Bt[m * 136 + qd * 8];
    #pragma unroll
    for (int kk = 0; kk < 4; kk++) {
        short8 af = *(const short8*)(ap + kk * 32);
        #pragma unroll
        for (int c = 0; c < 8; c++) {
            short8 bf = *(const short8*)(bp + c * 16 * 136 + kk * 32);
            acc[c] = __builtin_amdgcn_mfma_f32_16x16x32_bf16(af, bf, acc[c], 0, 0, 0);
        }
    }
    #pragma unroll
    for (int reg = 0; reg < 4; reg++) {       // D[row=qd*4+reg][col=16c+m]
        int g = row0 + wv * 16 + qd * 4 + reg;
        if (g < N_NODES) {
            #pragma unroll
            for (int c = 0; c < 8; c++)
                h1s[g * 128 + c * 16 + m] = f2b(acc[c][reg]);
        } else {                              // zero pad rows (branchless-agg target)
            #pragma unroll
            for (int c = 0; c < 8; c++)
                h1s[g * 128 + c * 16 + m] = 0;
            #pragma unroll
            for (int c = 0; c < 4; c++)
                h2s[g * 64 + c * 16 + m] = 0;
        }
    }
}

// ---------- 5. fused agg1 + GEMM2 ----------
// agg: r1[v] = relu(dv * (Σ dinv[s]·h1s[s] + dv·h1s[v]) + b1) -> LDS A-tile
// (16 nodes/block). h1s is UNSCALED; dinv[s] gathered from counts and broadcast
// with the neighbor index. Then 1 MFMA col-tile/wave.
__global__ __launch_bounds__(256) void k_agg1g2(const unsigned short* __restrict__ h1s,
                                                const unsigned short* __restrict__ Wt2,
                                                const int* __restrict__ csr,
                                                const int* __restrict__ counts,
                                                const float* __restrict__ b1,
                                                unsigned short* __restrict__ h2s) {
    __shared__ unsigned short Bt[64 * 136];   // Wt2 [n=64][k=128] staged
    __shared__ unsigned short At[16 * 136];   // r1 tile [16 rows][128 k]
    int t = threadIdx.x;
    for (int i = t; i < 1024; i += 256) {     // stage Bt2
        int n = i >> 4, kc = (i & 15) * 8;
        *(uint4*)&Bt[n * 136 + kc] = *(const uint4*)(Wt2 + n * 128 + kc);
    }
    int wv = t >> 6, lane = t & 63;
    int q = lane >> 4, l = lane & 15;
    int v0 = blockIdx.x * 16;
    int v = v0 + wv * 4 + q;                  // 50000 = 3125*16: always valid
    int n = counts[v];
    float dv = rsqrtf((float)n + 1.0f);
    int n_eff = min(n, CAP);
    const int* cs = csr + v * CAP;
    int nmax = n_eff;
    nmax = max(nmax, __shfl_xor(nmax, 16));
    nmax = max(nmax, __shfl_xor(nmax, 32));
    float a0, a1, a2, a3, a4, a5, a6, a7;
    {   // self-loop row: dv * h1s[v] (h1s unscaled)
        uint4 p = *(const uint4*)(h1s + v * 128 + l * 8);
        a0 = dv * bflo(p.x); a1 = dv * bfhi(p.x); a2 = dv * bflo(p.y); a3 = dv * bfhi(p.y);
        a4 = dv * bflo(p.z); a5 = dv * bfhi(p.z); a6 = dv * bflo(p.w); a7 = dv * bfhi(p.w);
    }
    for (int base = 0; base < nmax; base += 16) {
        int idx = base + l;
        int e = (idx < n_eff) ? cs[idx] : ZROW;     // pad -> zero row
        float de = rsqrtf((float)counts[e] + 1.0f); // counts[ZROW]=0 -> de=1, row=0
        int mm = nmax - base; if (mm > 16) mm = 16;
        #pragma unroll 4
        for (int i = 0; i < mm; i++) {
            int s = __shfl(e, (q << 4) + i);        // ZROW contributes exact 0.0f
            float di = __shfl(de, (q << 4) + i);
            uint4 p = *(const uint4*)(h1s + s * 128 + l * 8);
            a0 = fmaf(di, bflo(p.x), a0); a1 = fmaf(di, bfhi(p.x), a1);
            a2 = fmaf(di, bflo(p.y), a2); a3 = fmaf(di, bfhi(p.y), a3);
            a4 = fmaf(di, bflo(p.z), a4); a5 = fmaf(di, bfhi(p.z), a5);
            a6 = fmaf(di, bflo(p.w), a6); a7 = fmaf(di, bfhi(p.w), a7);
        }
    }
    {
        float4 bL = *(const float4*)(b1 + l * 8);
        float4 bH = *(const float4*)(b1 + l * 8 + 4);
        a0 = fmaxf(fmaf(dv, a0, bL.x), 0.f); a1 = fmaxf(fmaf(dv, a1, bL.y), 0.f);
        a2 = fmaxf(fmaf(dv, a2, bL.z), 0.f); a3 = fmaxf(fmaf(dv, a3, bL.w), 0.f);
        a4 = fmaxf(fmaf(dv, a4, bH.x), 0.f); a5 = fmaxf(fmaf(dv, a5, bH.y), 0.f);
        a6 = fmaxf(fmaf(dv, a6, bH.z), 0.f); a7 = fmaxf(fmaf(dv, a7, bH.w), 0.f);
        uint4 o;
        o.x = (uint32_t)f2b(a0) | ((uint32_t)f2b(a1) << 16);
        o.y = (uint32_t)f2b(a2) | ((uint32_t)f2b(a3) << 16);
        o.z = (uint32_t)f2b(a4) | ((uint32_t)f2b(a5) << 16);
        o.w = (uint32_t)f2b(a6) | ((uint32_t)f2b(a7) << 16);
        *(uint4*)&At[(wv * 4 + q) * 136 + l * 8] = o;   // r1 tile row
    }
    __syncthreads();
    // MFMA: wave wv -> col-tile wv (cols 16wv..16wv+15)
    int m = lane & 15, qd = lane >> 4;
    floatx4 acc = (floatx4){0.f, 0.f, 0.f, 0.f};
    const unsigned short* ap = &At[m * 136 + qd * 8];
    const unsigned short* bp = &Bt[(wv * 16 + m) * 136 + qd * 8];
    #pragma unroll
    for (int kk = 0; kk < 4; kk++) {
        short8 af = *(const short8*)(ap + kk * 32);
        short8 bf = *(const short8*)(bp + kk * 32);
        acc = __builtin_amdgcn_mfma_f32_16x16x32_bf16(af, bf, acc, 0, 0, 0);
    }
    #pragma unroll
    for (int reg = 0; reg < 4; reg++) {
        int g = v0 + qd * 4 + reg;
        float dg = rsqrtf((float)counts[g] + 1.0f);   // prescale h2 rows
        h2s[g * 64 + wv * 16 + m] = f2b(dg * acc[reg]);
    }
}

// ---------- 6. agg2 + head (2 neighbors/iter) ----------
// 16-lane group: lanes split lo8/hi8, each half reads a full 128B row (8x16B)
// of one neighbor of the pair; halves combined with shfl_xor(8) at the end.
__global__ __launch_bounds__(256) void k_agg2(const unsigned short* __restrict__ h2s,
                                              const int* __restrict__ csr,
                                              const int* __restrict__ counts,
                                              const float* __restrict__ b2,
                                              const float* __restrict__ Wo,
                                              const float* __restrict__ bo,
                                              float* __restrict__ out) {
    int wave = (blockIdx.x * 256 + threadIdx.x) >> 6;
    int lane = threadIdx.x & 63;
    int q = lane >> 4, l = lane & 15;
    int h = l >> 3, c = l & 7;                // half, column-octet
    int v = wave * 4 + q;                     // 3125*4*4 = 50000: always valid
    int n = counts[v];
    float dv = rsqrtf((float)n + 1.0f);
    int n_eff = min(n, CAP);
    const int* cs = csr + v * CAP;
    int nmax = n_eff;
    nmax = max(nmax, __shfl_xor(nmax, 16));
    nmax = max(nmax, __shfl_xor(nmax, 32));
    float a0 = 0.f, a1 = 0.f, a2 = 0.f, a3 = 0.f, a4 = 0.f, a5 = 0.f, a6 = 0.f, a7 = 0.f;
    if (h == 0) {   // self-loop row (prescaled) into half 0 only
        uint4 p = *(const uint4*)(h2s + v * 64 + c * 8);
        a0 = bflo(p.x); a1 = bfhi(p.x); a2 = bflo(p.y); a3 = bfhi(p.y);
        a4 = bflo(p.z); a5 = bfhi(p.z); a6 = bflo(p.w); a7 = bfhi(p.w);
    }
    for (int base = 0; base < nmax; base += 16) {
        int idx = base + l;
        int e = (idx < n_eff) ? cs[idx] : ZROW;   // pad -> zero row (extra odd slot too)
        int mm = nmax - base; if (mm > 16) mm = 16;
        int pairs = (mm + 1) >> 1;
        #pragma unroll 4
        for (int i = 0; i < pairs; i++) {
            int s = __shfl(e, (q << 4) + 2 * i + h);   // half h takes pair element h
            uint4 p = *(const uint4*)(h2s + s * 64 + c * 8);
            a0 += bflo(p.x); a1 += bfhi(p.x); a2 += bflo(p.y); a3 += bfhi(p.y);
            a4 += bflo(p.z); a5 += bfhi(p.z); a6 += bflo(p.w); a7 += bfhi(p.w);
        }
    }
    // combine halves
    a0 += __shfl_xor(a0, 8); a1 += __shfl_xor(a1, 8);
    a2 += __shfl_xor(a2, 8); a3 += __shfl_xor(a3, 8);
    a4 += __shfl_xor(a4, 8); a5 += __shfl_xor(a5, 8);
    a6 += __shfl_xor(a6, 8); a7 += __shfl_xor(a7, 8);
    float4 bL = *(const float4*)(b2 + c * 8);
    float4 bH = *(const float4*)(b2 + c * 8 + 4);
    a0 = fmaxf(fmaf(dv, a0, bL.x), 0.f); a1 = fmaxf(fmaf(dv, a1, bL.y), 0.f);
    a2 = fmaxf(fmaf(dv, a2, bL.z), 0.f); a3 = fmaxf(fmaf(dv, a3, bL.w), 0.f);
    a4 = fmaxf(fmaf(dv, a4, bH.x), 0.f); a5 = fmaxf(fmaf(dv, a5, bH.y), 0.f);
    a6 = fmaxf(fmaf(dv, a6, bH.z), 0.f); a7 = fmaxf(fmaf(dv, a7, bH.w), 0.f);
    // head: logits over this lane's 8 cols (8c..8c+7), Wo row-major [64][2]
    float4 wA = *(const float4*)(Wo + c * 16);
    float4 wB = *(const float4*)(Wo + c * 16 + 4);
    float4 wC = *(const float4*)(Wo + c * 16 + 8);
    float4 wD = *(const float4*)(Wo + c * 16 + 12);
    float l0 = a0 * wA.x + a1 * wA.z + a2 * wB.x + a3 * wB.z
             + a4 * wC.x + a5 * wC.z + a6 * wD.x + a7 * wD.z;
    float l1 = a0 * wA.y + a1 * wA.w + a2 * wB.y + a3 * wB.w
             + a4 * wC.y + a5 * wC.w + a6 * wD.y + a7 * wD.w;
    l0 += __shfl_xor(l0, 1); l1 += __shfl_xor(l1, 1);
    l0 += __shfl_xor(l0, 2); l1 += __shfl_xor(l1, 2);
    l0 += __shfl_xor(l0, 4); l1 += __shfl_xor(l1, 4);
    if (l == 0) {
        float2 bof = *(const float2*)bo;
        l0 += bof.x; l1 += bof.y;
        float m = fmaxf(l0, l1);
        float ls = m + __logf(__expf(l0 - m) + __expf(l1 - m));
        *(float2*)(out + v * 2) = make_float2(l0 - ls, l1 - ls);
    }
}

extern "C" void kernel_launch(void* const* d_in, const int* in_sizes, int n_in,
                              void* d_out, int out_size, void* d_ws, size_t ws_size,
                              hipStream_t stream) {
    const float* x  = (const float*)d_in[0];
    const int* ei   = (const int*)d_in[1];
    const float* W1 = (const float*)d_in[2];
    const float* b1 = (const float*)d_in[3];
    const float* W2 = (const float*)d_in[4];
    const float* b2 = (const float*)d_in[5];
    const float* Wo = (const float*)d_in[6];
    const float* bo = (const float*)d_in[7];
    float* out      = (float*)d_out;
    const int* src = ei;             // edge_index[0]
    const int* dst = ei + N_EDGES;   // edge_index[1]

    char* w = (char*)d_ws;
    int* counts = (int*)(w + 0);                           // 200 KB (50176 ints; pads written 0 by CSR pass)
    int* csr    = (int*)(w + 200704);                      // 16 MB  [node][CAP]
    unsigned short* Wt1 = (unsigned short*)(w + 16200704); // 32 KB  [n=128][k=128]
    unsigned short* Wt2 = (unsigned short*)(w + 16233472); // 16 KB  [n=64][k=128]
    unsigned short* h1s = (unsigned short*)(w + 16249856); // 12.81 MB (50048 rows, pad zeroed)
    unsigned short* h2s = (unsigned short*)(w + 29062144); // 6.41 MB  (50048 rows, pad zeroed)
    int2* binned = (int2*)(w + 35468288);                  // 6.40 MB bin-ordered (src,dst)
    int* mat     = (int*)(w + 41868288);                   // 100 KB [blk=128][bin=196]
    int* binStart= (int*)(w + 41968640);                   // 788 B  [NBIN+1]
    // total ws usage: ~42 MB

    k_prep     <<<224, 256, 0, stream>>>(W1, W2, Wt1, Wt2, dst, mat);
    k_scan     <<<1, 256, 0, stream>>>(mat, binStart);
    k_binscat  <<<NBLK_A, 256, 0, stream>>>(src, dst, mat, binned);
    k_csr_gemm1<<<NBIN + GEMM_BLOCKS, 256, 0, stream>>>(binned, binStart, counts, csr,
                                                        x, Wt1, h1s, h2s);
    k_agg1g2   <<<3125, 256, 0, stream>>>(h1s, Wt2, csr, counts, b1, h2s);
    k_agg2     <<<3125, 256, 0, stream>>>(h2s, csr, counts, b2, Wo, bo, out);
}